// Round 10
// baseline (57.991 us; speedup 1.0000x reference)
//
#include <hip/hip_runtime.h>
#include <math.h>

// Problem constants (B=2, N=4096, T=2048, E=8192, MAX_DELAY=64)
static constexpr int NN = 4096;
static constexpr int TT = 2048;
static constexpr int EE = 8192;
static constexpr int TK = 64;
static constexpr int CAP = 32;                  // max in-degree (Poisson lam=2)
static constexpr int HALO = 80;                 // zero halo (lookback 79)
static constexpr int TABS = 96;                 // Toeplitz row stride (proven r3-r8)

typedef __attribute__((ext_vector_type(8))) short        short8v;  // 8 bf16
typedef __attribute__((ext_vector_type(4))) float        float4v;  // MFMA acc

__device__ __forceinline__ unsigned cvtpk_bf16(float lo, float hi) {
    unsigned r;                      // D[15:0]=bf16(lo), D[31:16]=bf16(hi), RNE
    asm("v_cvt_pk_bf16_f32 %0, %1, %2" : "=v"(r) : "v"(lo), "v"(hi));
    return r;
}
__device__ __forceinline__ float bf2f(unsigned short u) {
    union { unsigned u; float f; } v; v.u = ((unsigned)u) << 16; return v.f;
}

// ---------------------------------------------------------------------------
// LDS layout shared by both conv passes: one halo'd bf16 row + K-Toeplitz tab.
//   y[16a+r] = sum_{delta,p} tab[r][80+16*delta+p-...] pattern, i.e.
//   tab[r][80+c] = K[r-c] (zeros outside [0,64)), staged row at xrow[HALO+t].
// ---------------------------------------------------------------------------
struct __align__(16) ConvLds {
    unsigned short xrow[HALO + TT];             // 2128 elems, 4256 B
    unsigned short tab[16 * TABS];              // 3072 B
};                                              // 7328 B/block

// init-time zero entries (value band is disjoint; proven r3-r8)
#define TAB_ZERO_INIT(lds)                                            \
    {                                                                 \
        int z_ = tid & 15;                                            \
        _Pragma("unroll")                                             \
        for (int rr_ = 0; rr_ < 2; ++rr_) {                           \
            int r2_ = (tid >> 4) + 8 * rr_;                           \
            (lds).tab[TABS * r2_ + z_] = 0;                           \
            (lds).tab[TABS * r2_ + ((z_ <= r2_) ? z_ + 16 : 80 + z_)] = 0; \
        }                                                             \
    }

// per-kernel value band: lane l holds K[l] (bf16), writes 16 rows
#define TAB_VALUE(lds, kb)                                            \
    {                                                                 \
        int rg_ = tid >> 6;                                           \
        _Pragma("unroll")                                             \
        for (int rr_ = 0; rr_ < 8; ++rr_) {                           \
            int r_ = rg_ * 8 + rr_;                                   \
            (lds).tab[TABS * r_ + 80 + r_ - l] = (kb);                \
        }                                                             \
    }

// 12 MFMAs: acc[T] += C-tab x staged-row  (proven r3-r8 fragment layout)
#define CONV_COMPUTE(lds, acc)                                        \
    {                                                                 \
        const unsigned short* tab_ = (lds).tab;                       \
        const unsigned short* xv_  = (lds).xrow;                      \
        const int abase_ = TABS * lane16 + 80 + 8 * hlo;              \
        short8v A0 = *reinterpret_cast<const short8v*>(&tab_[abase_ - 16 * (0 + hhi)]); \
        short8v A1 = *reinterpret_cast<const short8v*>(&tab_[abase_ - 16 * (2 + hhi)]); \
        short8v A2 = *reinterpret_cast<const short8v*>(&tab_[abase_ - 16 * (4 + hhi)]); \
        _Pragma("unroll")                                             \
        for (int T = 0; T < 4; ++T) {                                 \
            const int bb_ = HALO + 16 * (64 * half + 16 * T + lane16) + 8 * hlo; \
            short8v B0 = *reinterpret_cast<const short8v*>(&xv_[bb_ - 16 * (0 + hhi)]); \
            acc[T] = __builtin_amdgcn_mfma_f32_16x16x32_bf16(A0, B0, acc[T], 0, 0, 0); \
            short8v B1 = *reinterpret_cast<const short8v*>(&xv_[bb_ - 16 * (2 + hhi)]); \
            acc[T] = __builtin_amdgcn_mfma_f32_16x16x32_bf16(A1, B1, acc[T], 0, 0, 0); \
            short8v B2 = *reinterpret_cast<const short8v*>(&xv_[bb_ - 16 * (4 + hhi)]); \
            acc[T] = __builtin_amdgcn_mfma_f32_16x16x32_bf16(A2, B2, acc[T], 0, 0, 0); \
        }                                                             \
    }

// ---------------------------------------------------------------------------
// K1: IRF -> hb bf16 (blocks [0,1024)) + edge scatter by target ([1024,1056)).
// cnt is zeroed by hipMemsetAsync before this launch.
// ---------------------------------------------------------------------------
__global__ void prep_kernel(const float* __restrict__ params,
                            const int* __restrict__ esrc, const int* __restrict__ etgt,
                            unsigned short* __restrict__ hb,
                            int* __restrict__ cnt, int* __restrict__ slist) {
    int blk = blockIdx.x;
    if (blk < 1024) {                           // IRF: node = thread/64, lane = tau
        int t = blk * 256 + threadIdx.x;
        int node = t >> 6, lane = t & 63;
        float p = params[node * 2];
        float sp = fmaxf(p, 0.f) + log1pf(expf(-fabsf(p)));   // stable softplus
        float kst = sp + 0.1f;
        float inv = 1.0f / kst;
        float hv = expf(-(float)lane * inv) * inv;
        float s = hv;
        #pragma unroll
        for (int d = 1; d < 64; d <<= 1) s += __shfl_xor(s, d, 64);
        float val = hv / s;
        hb[node * TK + lane] = (unsigned short)(cvtpk_bf16(val, val) & 0xffffu);
    } else {                                    // scatter: 32 blk x 256 = 8192 edges
        int e = (blk - 1024) * 256 + threadIdx.x;
        int t = etgt[e], s = esrc[e];
        int pos = atomicAdd(&cnt[t], 1);
        if (pos < CAP) slist[t * CAP + pos] = s;
    }
}

// ---------------------------------------------------------------------------
// K2 (pass A): z[n] = h_n (*) x_n  for all (node, batch) rows; z stored bf16.
// One block per (node, batch), 128 thr = 2 waves (wave = time half).
// ---------------------------------------------------------------------------
__global__ __launch_bounds__(128)
void passA_kernel(const float* __restrict__ x,
                  const unsigned short* __restrict__ hb,
                  unsigned short* __restrict__ z) {
    __shared__ ConvLds lds;
    const int tid    = threadIdx.x;
    const int bid    = blockIdx.x;
    const int b      = bid & 1;
    const int node   = bid >> 1;
    const int l      = tid & 63;
    const int lane16 = l & 15;
    const int h      = l >> 4;
    const int hlo    = h & 1, hhi = h >> 1;
    const int half   = tid >> 6;

    // issue global loads first
    const float4* xr = reinterpret_cast<const float4*>(x + ((size_t)b * NN + node) * TT);
    float4 px[4];
    #pragma unroll
    for (int c = 0; c < 4; ++c) px[c] = xr[tid + 128 * c];
    unsigned short kb = hb[(size_t)node * TK + l];

    // LDS init under the load latency
    for (int idx = tid; idx < HALO; idx += 128) lds.xrow[idx] = 0;
    TAB_ZERO_INIT(lds);

    // stage row (fp32 -> bf16) + tab value band
    #pragma unroll
    for (int c = 0; c < 4; ++c) {
        int u = tid + 128 * c;
        unsigned lo = cvtpk_bf16(px[c].x, px[c].y);
        unsigned hi = cvtpk_bf16(px[c].z, px[c].w);
        *reinterpret_cast<uint2*>(&lds.xrow[HALO + 4 * u]) = make_uint2(lo, hi);
    }
    TAB_VALUE(lds, kb);
    __syncthreads();

    float4v acc[4];
    #pragma unroll
    for (int T = 0; T < 4; ++T) acc[T] = (float4v){0.f, 0.f, 0.f, 0.f};
    CONV_COMPUTE(lds, acc);

    unsigned short* zr = z + ((size_t)b * NN + node) * TT;
    #pragma unroll
    for (int T = 0; T < 4; ++T) {
        int tb = 16 * (64 * half + 16 * T + lane16) + 4 * h;
        uint2 o = make_uint2(cvtpk_bf16(acc[T][0], acc[T][1]),
                             cvtpk_bf16(acc[T][2], acc[T][3]));
        *reinterpret_cast<uint2*>(&zr[tb]) = o;   // cacheable: re-read by pass B
    }
}

// ---------------------------------------------------------------------------
// K3 (pass B): w = x_tgt + sum_e z[src_e];  y[tgt] = h_tgt (*) w.
// One block per (tgt, batch), 128 thr = 2 waves.  fp32 accumulation in regs;
// w staged bf16 into LDS; same polyphase conv; y stored fp32 nontemporal.
// Thread owns elems {8*tid..8*tid+7} and {1024+8*tid..+7} of the row.
// ---------------------------------------------------------------------------
__global__ __launch_bounds__(128)
void passB_kernel(const float* __restrict__ x,
                  const unsigned short* __restrict__ z,
                  const unsigned short* __restrict__ hb,
                  const int* __restrict__ slist,
                  const int* __restrict__ cnt,
                  float* __restrict__ y) {
    __shared__ ConvLds lds;
    const int tid    = threadIdx.x;
    const int bid    = blockIdx.x;
    const int b      = bid & 1;
    const int tgt    = bid >> 1;
    const int l      = tid & 63;
    const int lane16 = l & 15;
    const int h      = l >> 4;
    const int hlo    = h & 1, hhi = h >> 1;
    const int half   = tid >> 6;

    // issue x loads + metadata first
    const float4* xr = reinterpret_cast<const float4*>(x + ((size_t)b * NN + tgt) * TT);
    float4 xa = xr[2 * tid], xb4 = xr[2 * tid + 1];
    float4 xc = xr[2 * tid + 256], xd = xr[2 * tid + 257];
    unsigned short kb = hb[(size_t)tgt * TK + l];
    int deg = __builtin_amdgcn_readfirstlane(cnt[tgt]);
    if (deg > CAP) deg = CAP;
    int sCur = 0;
    if (deg > 0) sCur = __builtin_amdgcn_readfirstlane(slist[tgt * CAP]);

    // LDS init under load latency
    for (int idx = tid; idx < HALO; idx += 128) lds.xrow[idx] = 0;
    TAB_ZERO_INIT(lds);

    float w[16];
    w[0] = xa.x;  w[1] = xa.y;  w[2] = xa.z;  w[3] = xa.w;
    w[4] = xb4.x; w[5] = xb4.y; w[6] = xb4.z; w[7] = xb4.w;
    w[8] = xc.x;  w[9] = xc.y;  w[10] = xc.z; w[11] = xc.w;
    w[12] = xd.x; w[13] = xd.y; w[14] = xd.z; w[15] = xd.w;

    for (int j = 0; j < deg; ++j) {
        const short8v* zr = reinterpret_cast<const short8v*>(z + ((size_t)b * NN + sCur) * TT);
        short8v z0 = zr[tid];
        short8v z1 = zr[tid + 128];
        if (j + 1 < deg) sCur = __builtin_amdgcn_readfirstlane(slist[tgt * CAP + j + 1]);
        #pragma unroll
        for (int k = 0; k < 8; ++k) {
            w[k]     += bf2f((unsigned short)z0[k]);
            w[8 + k] += bf2f((unsigned short)z1[k]);
        }
    }

    // stage w (bf16) + tab value band
    {
        uint4 o;
        o.x = cvtpk_bf16(w[0], w[1]); o.y = cvtpk_bf16(w[2], w[3]);
        o.z = cvtpk_bf16(w[4], w[5]); o.w = cvtpk_bf16(w[6], w[7]);
        *reinterpret_cast<uint4*>(&lds.xrow[HALO + 8 * tid]) = o;
        o.x = cvtpk_bf16(w[8], w[9]);   o.y = cvtpk_bf16(w[10], w[11]);
        o.z = cvtpk_bf16(w[12], w[13]); o.w = cvtpk_bf16(w[14], w[15]);
        *reinterpret_cast<uint4*>(&lds.xrow[HALO + 1024 + 8 * tid]) = o;
    }
    TAB_VALUE(lds, kb);
    __syncthreads();

    float4v acc[4];
    #pragma unroll
    for (int T = 0; T < 4; ++T) acc[T] = (float4v){0.f, 0.f, 0.f, 0.f};
    CONV_COMPUTE(lds, acc);

    float* yrow = y + ((size_t)b * NN + tgt) * TT;
    #pragma unroll
    for (int T = 0; T < 4; ++T) {
        int tb = 16 * (64 * half + 16 * T + lane16) + 4 * h;
        float4v v = acc[T];
        __builtin_nontemporal_store(v, reinterpret_cast<float4v*>(yrow + tb));
    }
}

// ---------------------------------------------------------------------------
extern "C" void kernel_launch(void* const* d_in, const int* in_sizes, int n_in,
                              void* d_out, int out_size, void* d_ws, size_t ws_size,
                              hipStream_t stream) {
    const float* x      = (const float*)d_in[0];
    const float* params = (const float*)d_in[1];
    const int*   esrc   = (const int*)d_in[2];
    const int*   etgt   = (const int*)d_in[3];
    float* y = (float*)d_out;

    char* w = (char*)d_ws;
    unsigned short* hb    = (unsigned short*)w; w += (size_t)NN * TK * 2;       // 0.5 MB
    int*            cnt   = (int*)w;            w += (size_t)NN * 4;            // 16 KB
    int*            slist = (int*)w;            w += (size_t)NN * CAP * 4;      // 0.5 MB
    unsigned short* z     = (unsigned short*)w; w += (size_t)2 * NN * TT * 2;   // 32 MB
    (void)ws_size;

    hipMemsetAsync(cnt, 0, (size_t)NN * 4, stream);
    hipLaunchKernelGGL(prep_kernel, dim3(1056), dim3(256), 0, stream,
                       params, esrc, etgt, hb, cnt, slist);
    hipLaunchKernelGGL(passA_kernel, dim3(NN * 2), dim3(128), 0, stream, x, hb, z);
    hipLaunchKernelGGL(passB_kernel, dim3(NN * 2), dim3(128), 0, stream,
                       x, z, hb, slist, cnt, y);
}

// Round 11
// 52.275 us; speedup vs baseline: 1.1093x; 1.1093x over previous
//
#include <hip/hip_runtime.h>
#include <math.h>

// Problem constants (B=2, N=4096, T=2048, E=8192, MAX_DELAY=64)
static constexpr int NN = 4096;
static constexpr int TT = 2048;
static constexpr int EE = 8192;
static constexpr int TK = 64;
static constexpr int CAP = 32;                  // max in-degree (Poisson lam=2)
static constexpr int HALO = 80;                 // zero halo (lookback 79)
static constexpr int TABS = 96;                 // Toeplitz row stride (proven r3-r10)

typedef __attribute__((ext_vector_type(8))) short        short8v;  // 8 bf16
typedef __attribute__((ext_vector_type(4))) float        float4v;  // MFMA acc

__device__ __forceinline__ unsigned cvtpk_bf16(float lo, float hi) {
    unsigned r;                      // D[15:0]=bf16(lo), D[31:16]=bf16(hi), RNE
    asm("v_cvt_pk_bf16_f32 %0, %1, %2" : "=v"(r) : "v"(lo), "v"(hi));
    return r;
}
__device__ __forceinline__ float bf2f(unsigned short u) {
    union { unsigned u; float f; } v; v.u = ((unsigned)u) << 16; return v.f;
}

// ---------------------------------------------------------------------------
// Shared LDS layout: one halo'd bf16 row + K-Toeplitz tab.
//   tab[r][80+c] = K[r-c] (zeros outside [0,64)); staged row at xrow[HALO+t].
// ---------------------------------------------------------------------------
struct __align__(16) ConvLds {
    unsigned short xrow[HALO + TT];             // 2128 elems, 4256 B
    unsigned short tab[16 * TABS];              // 3072 B
};                                              // 7328 B/block

#define TAB_ZERO_INIT(lds)                                            \
    {                                                                 \
        int z_ = tid & 15;                                            \
        _Pragma("unroll")                                             \
        for (int rr_ = 0; rr_ < 2; ++rr_) {                           \
            int r2_ = (tid >> 4) + 8 * rr_;                           \
            (lds).tab[TABS * r2_ + z_] = 0;                           \
            (lds).tab[TABS * r2_ + ((z_ <= r2_) ? z_ + 16 : 80 + z_)] = 0; \
        }                                                             \
    }

#define TAB_VALUE(lds, kb)                                            \
    {                                                                 \
        int rg_ = tid >> 6;                                           \
        _Pragma("unroll")                                             \
        for (int rr_ = 0; rr_ < 8; ++rr_) {                           \
            int r_ = rg_ * 8 + rr_;                                   \
            (lds).tab[TABS * r_ + 80 + r_ - l] = (kb);                \
        }                                                             \
    }

#define CONV_COMPUTE(lds, acc)                                        \
    {                                                                 \
        const unsigned short* tab_ = (lds).tab;                       \
        const unsigned short* xv_  = (lds).xrow;                      \
        const int abase_ = TABS * lane16 + 80 + 8 * hlo;              \
        short8v A0 = *reinterpret_cast<const short8v*>(&tab_[abase_ - 16 * (0 + hhi)]); \
        short8v A1 = *reinterpret_cast<const short8v*>(&tab_[abase_ - 16 * (2 + hhi)]); \
        short8v A2 = *reinterpret_cast<const short8v*>(&tab_[abase_ - 16 * (4 + hhi)]); \
        _Pragma("unroll")                                             \
        for (int T = 0; T < 4; ++T) {                                 \
            const int bb_ = HALO + 16 * (64 * half + 16 * T + lane16) + 8 * hlo; \
            short8v B0 = *reinterpret_cast<const short8v*>(&xv_[bb_ - 16 * (0 + hhi)]); \
            acc[T] = __builtin_amdgcn_mfma_f32_16x16x32_bf16(A0, B0, acc[T], 0, 0, 0); \
            short8v B1 = *reinterpret_cast<const short8v*>(&xv_[bb_ - 16 * (2 + hhi)]); \
            acc[T] = __builtin_amdgcn_mfma_f32_16x16x32_bf16(A1, B1, acc[T], 0, 0, 0); \
            short8v B2 = *reinterpret_cast<const short8v*>(&xv_[bb_ - 16 * (4 + hhi)]); \
            acc[T] = __builtin_amdgcn_mfma_f32_16x16x32_bf16(A2, B2, acc[T], 0, 0, 0); \
        }                                                             \
    }

// ---------------------------------------------------------------------------
// K1: IRF -> hb bf16 (blocks [0,1024)) + edge scatter by target ([1024,1056)).
// cnt zeroed by hipMemsetAsync before this launch.
// ---------------------------------------------------------------------------
__global__ void prep_kernel(const float* __restrict__ params,
                            const int* __restrict__ esrc, const int* __restrict__ etgt,
                            unsigned short* __restrict__ hb,
                            int* __restrict__ cnt, int* __restrict__ slist) {
    int blk = blockIdx.x;
    if (blk < 1024) {                           // IRF: node = thread/64, lane = tau
        int t = blk * 256 + threadIdx.x;
        int node = t >> 6, lane = t & 63;
        float p = params[node * 2];
        float sp = fmaxf(p, 0.f) + log1pf(expf(-fabsf(p)));   // stable softplus
        float kst = sp + 0.1f;
        float inv = 1.0f / kst;
        float hv = expf(-(float)lane * inv) * inv;
        float s = hv;
        #pragma unroll
        for (int d = 1; d < 64; d <<= 1) s += __shfl_xor(s, d, 64);
        float val = hv / s;
        hb[node * TK + lane] = (unsigned short)(cvtpk_bf16(val, val) & 0xffffu);
    } else {                                    // scatter: 32 blk x 256 = 8192 edges
        int e = (blk - 1024) * 256 + threadIdx.x;
        int t = etgt[e], s = esrc[e];
        int pos = atomicAdd(&cnt[t], 1);
        if (pos < CAP) slist[t * CAP + pos] = s;
    }
}

// ---------------------------------------------------------------------------
// K2 (pass A): z[n] = h_n (*) x_n  for all (node, batch) rows; z stored bf16
// with PLAIN stores (re-read by pass B -> keep cacheable).
// ---------------------------------------------------------------------------
__global__ __launch_bounds__(128)
void passA_kernel(const float* __restrict__ x,
                  const unsigned short* __restrict__ hb,
                  unsigned short* __restrict__ z) {
    __shared__ ConvLds lds;
    const int tid    = threadIdx.x;
    const int bid    = blockIdx.x;
    const int b      = bid & 1;
    const int node   = bid >> 1;
    const int l      = tid & 63;
    const int lane16 = l & 15;
    const int h      = l >> 4;
    const int hlo    = h & 1, hhi = h >> 1;
    const int half   = tid >> 6;

    const float4* xr = reinterpret_cast<const float4*>(x + ((size_t)b * NN + node) * TT);
    float4 px[4];
    #pragma unroll
    for (int c = 0; c < 4; ++c) px[c] = xr[tid + 128 * c];
    unsigned short kb = hb[(size_t)node * TK + l];

    for (int idx = tid; idx < HALO; idx += 128) lds.xrow[idx] = 0;
    TAB_ZERO_INIT(lds);

    #pragma unroll
    for (int c = 0; c < 4; ++c) {
        int u = tid + 128 * c;
        unsigned lo = cvtpk_bf16(px[c].x, px[c].y);
        unsigned hi = cvtpk_bf16(px[c].z, px[c].w);
        *reinterpret_cast<uint2*>(&lds.xrow[HALO + 4 * u]) = make_uint2(lo, hi);
    }
    TAB_VALUE(lds, kb);
    __syncthreads();

    float4v acc[4];
    #pragma unroll
    for (int T = 0; T < 4; ++T) acc[T] = (float4v){0.f, 0.f, 0.f, 0.f};
    CONV_COMPUTE(lds, acc);

    unsigned short* zr = z + ((size_t)b * NN + node) * TT;
    #pragma unroll
    for (int T = 0; T < 4; ++T) {
        int tb = 16 * (64 * half + 16 * T + lane16) + 4 * h;
        uint2 o = make_uint2(cvtpk_bf16(acc[T][0], acc[T][1]),
                             cvtpk_bf16(acc[T][2], acc[T][3]));
        *reinterpret_cast<uint2*>(&zr[tb]) = o;
    }
}

// ---------------------------------------------------------------------------
// K3 (pass B): y[tgt] = z_tgt + h_tgt (*) (sum_e z[src_e]).   NO x read.
// One block per (tgt, batch), 128 thr = 2 waves.  Gathered sum in fp32 regs,
// staged bf16; z_tgt loaded in the ACC OUTPUT layout (uint2 per T) and added
// after the conv (it is already convolved — passA output).
// ---------------------------------------------------------------------------
__global__ __launch_bounds__(128)
void passB_kernel(const unsigned short* __restrict__ z,
                  const unsigned short* __restrict__ hb,
                  const int* __restrict__ slist,
                  const int* __restrict__ cnt,
                  float* __restrict__ y) {
    __shared__ ConvLds lds;
    const int tid    = threadIdx.x;
    const int bid    = blockIdx.x;
    const int b      = bid & 1;
    const int tgt    = bid >> 1;
    const int l      = tid & 63;
    const int lane16 = l & 15;
    const int h      = l >> 4;
    const int hlo    = h & 1, hhi = h >> 1;
    const int half   = tid >> 6;

    // issue z_tgt (output-layout) + metadata loads first
    const unsigned short* ztr = z + ((size_t)b * NN + tgt) * TT;
    uint2 zt[4];
    #pragma unroll
    for (int T = 0; T < 4; ++T) {
        int tb = 16 * (64 * half + 16 * T + lane16) + 4 * h;
        zt[T] = *reinterpret_cast<const uint2*>(&ztr[tb]);
    }
    unsigned short kb = hb[(size_t)tgt * TK + l];
    int deg = __builtin_amdgcn_readfirstlane(cnt[tgt]);
    if (deg > CAP) deg = CAP;
    int sCur = 0;
    if (deg > 0) sCur = __builtin_amdgcn_readfirstlane(slist[tgt * CAP]);

    // LDS init under load latency
    for (int idx = tid; idx < HALO; idx += 128) lds.xrow[idx] = 0;
    TAB_ZERO_INIT(lds);

    // gather sum_e z_src in fp32 (thread owns elems 8*tid.. and 1024+8*tid..)
    float w[16];
    #pragma unroll
    for (int k = 0; k < 16; ++k) w[k] = 0.f;
    for (int j = 0; j < deg; ++j) {
        const short8v* zr = reinterpret_cast<const short8v*>(z + ((size_t)b * NN + sCur) * TT);
        short8v z0 = zr[tid];
        short8v z1 = zr[tid + 128];
        if (j + 1 < deg) sCur = __builtin_amdgcn_readfirstlane(slist[tgt * CAP + j + 1]);
        #pragma unroll
        for (int k = 0; k < 8; ++k) {
            w[k]     += bf2f((unsigned short)z0[k]);
            w[8 + k] += bf2f((unsigned short)z1[k]);
        }
    }

    // stage w (bf16) + tab value band
    {
        uint4 o;
        o.x = cvtpk_bf16(w[0], w[1]); o.y = cvtpk_bf16(w[2], w[3]);
        o.z = cvtpk_bf16(w[4], w[5]); o.w = cvtpk_bf16(w[6], w[7]);
        *reinterpret_cast<uint4*>(&lds.xrow[HALO + 8 * tid]) = o;
        o.x = cvtpk_bf16(w[8], w[9]);   o.y = cvtpk_bf16(w[10], w[11]);
        o.z = cvtpk_bf16(w[12], w[13]); o.w = cvtpk_bf16(w[14], w[15]);
        *reinterpret_cast<uint4*>(&lds.xrow[HALO + 1024 + 8 * tid]) = o;
    }
    TAB_VALUE(lds, kb);
    __syncthreads();

    float4v acc[4];
    #pragma unroll
    for (int T = 0; T < 4; ++T) acc[T] = (float4v){0.f, 0.f, 0.f, 0.f};
    CONV_COMPUTE(lds, acc);

    float* yrow = y + ((size_t)b * NN + tgt) * TT;
    #pragma unroll
    for (int T = 0; T < 4; ++T) {
        int tb = 16 * (64 * half + 16 * T + lane16) + 4 * h;
        float4v v = acc[T];
        v[0] += bf2f((unsigned short)(zt[T].x & 0xffffu));
        v[1] += bf2f((unsigned short)(zt[T].x >> 16));
        v[2] += bf2f((unsigned short)(zt[T].y & 0xffffu));
        v[3] += bf2f((unsigned short)(zt[T].y >> 16));
        __builtin_nontemporal_store(v, reinterpret_cast<float4v*>(yrow + tb));
    }
}

// ---------------------------------------------------------------------------
extern "C" void kernel_launch(void* const* d_in, const int* in_sizes, int n_in,
                              void* d_out, int out_size, void* d_ws, size_t ws_size,
                              hipStream_t stream) {
    const float* x      = (const float*)d_in[0];
    const float* params = (const float*)d_in[1];
    const int*   esrc   = (const int*)d_in[2];
    const int*   etgt   = (const int*)d_in[3];
    float* y = (float*)d_out;

    char* w = (char*)d_ws;
    unsigned short* hb    = (unsigned short*)w; w += (size_t)NN * TK * 2;       // 0.5 MB
    int*            cnt   = (int*)w;            w += (size_t)NN * 4;            // 16 KB
    int*            slist = (int*)w;            w += (size_t)NN * CAP * 4;      // 0.5 MB
    unsigned short* z     = (unsigned short*)w; w += (size_t)2 * NN * TT * 2;   // 32 MB
    (void)ws_size;

    hipMemsetAsync(cnt, 0, (size_t)NN * 4, stream);
    hipLaunchKernelGGL(prep_kernel, dim3(1056), dim3(256), 0, stream,
                       params, esrc, etgt, hb, cnt, slist);
    hipLaunchKernelGGL(passA_kernel, dim3(NN * 2), dim3(128), 0, stream, x, hb, z);
    hipLaunchKernelGGL(passB_kernel, dim3(NN * 2), dim3(128), 0, stream,
                       z, hb, slist, cnt, y);
}

// Round 12
// 48.892 us; speedup vs baseline: 1.1861x; 1.0692x over previous
//
#include <hip/hip_runtime.h>
#include <math.h>

// Problem constants (B=2, N=4096, T=2048, E=8192, MAX_DELAY=64)
static constexpr int NN = 4096;
static constexpr int TT = 2048;
static constexpr int EE = 8192;
static constexpr int TK = 64;
static constexpr int CAP = 32;                  // max in-degree (Poisson lam=2)
static constexpr int HALO = 80;                 // zero halo (lookback 79)
static constexpr int TABS = 96;                 // Toeplitz row stride (proven r3-r11)

typedef __attribute__((ext_vector_type(8))) short        short8v;  // 8 bf16
typedef __attribute__((ext_vector_type(4))) float        float4v;  // MFMA acc

__device__ __forceinline__ unsigned cvtpk_bf16(float lo, float hi) {
    unsigned r;                      // D[15:0]=bf16(lo), D[31:16]=bf16(hi), RNE
    asm("v_cvt_pk_bf16_f32 %0, %1, %2" : "=v"(r) : "v"(lo), "v"(hi));
    return r;
}
__device__ __forceinline__ float bf2f(unsigned short u) {
    union { unsigned u; float f; } v; v.u = ((unsigned)u) << 16; return v.f;
}

// inline per-node IRF: lane l returns bf16(h[node][l]); ~40 VALU + shuffle tree,
// fully hidden under the block's global-load latency.  Same math as prior rounds.
__device__ __forceinline__ unsigned short irf_lane(const float* __restrict__ params,
                                                   int node, int l) {
    float p = params[node * 2];
    float sp = fmaxf(p, 0.f) + log1pf(expf(-fabsf(p)));       // stable softplus
    float kst = sp + 0.1f;
    float inv = 1.0f / kst;
    float hv = expf(-(float)l * inv) * inv;
    float s = hv;
    #pragma unroll
    for (int d = 1; d < 64; d <<= 1) s += __shfl_xor(s, d, 64);
    float val = hv / s;
    return (unsigned short)(cvtpk_bf16(val, val) & 0xffffu);
}

// ---------------------------------------------------------------------------
// Shared LDS layout: one halo'd bf16 row + K-Toeplitz tab.
//   tab[r][80+c] = K[r-c] (zeros outside [0,64)); staged row at xrow[HALO+t].
// ---------------------------------------------------------------------------
struct __align__(16) ConvLds {
    unsigned short xrow[HALO + TT];             // 2128 elems, 4256 B
    unsigned short tab[16 * TABS];              // 3072 B
};                                              // 7328 B/block

#define TAB_ZERO_INIT(lds)                                            \
    {                                                                 \
        int z_ = tid & 15;                                            \
        _Pragma("unroll")                                             \
        for (int rr_ = 0; rr_ < 2; ++rr_) {                           \
            int r2_ = (tid >> 4) + 8 * rr_;                           \
            (lds).tab[TABS * r2_ + z_] = 0;                           \
            (lds).tab[TABS * r2_ + ((z_ <= r2_) ? z_ + 16 : 80 + z_)] = 0; \
        }                                                             \
    }

#define TAB_VALUE(lds, kb)                                            \
    {                                                                 \
        int rg_ = tid >> 6;                                           \
        _Pragma("unroll")                                             \
        for (int rr_ = 0; rr_ < 8; ++rr_) {                           \
            int r_ = rg_ * 8 + rr_;                                   \
            (lds).tab[TABS * r_ + 80 + r_ - l] = (kb);                \
        }                                                             \
    }

#define CONV_COMPUTE(lds, acc)                                        \
    {                                                                 \
        const unsigned short* tab_ = (lds).tab;                       \
        const unsigned short* xv_  = (lds).xrow;                      \
        const int abase_ = TABS * lane16 + 80 + 8 * hlo;              \
        short8v A0 = *reinterpret_cast<const short8v*>(&tab_[abase_ - 16 * (0 + hhi)]); \
        short8v A1 = *reinterpret_cast<const short8v*>(&tab_[abase_ - 16 * (2 + hhi)]); \
        short8v A2 = *reinterpret_cast<const short8v*>(&tab_[abase_ - 16 * (4 + hhi)]); \
        _Pragma("unroll")                                             \
        for (int T = 0; T < 4; ++T) {                                 \
            const int bb_ = HALO + 16 * (64 * half + 16 * T + lane16) + 8 * hlo; \
            short8v B0 = *reinterpret_cast<const short8v*>(&xv_[bb_ - 16 * (0 + hhi)]); \
            acc[T] = __builtin_amdgcn_mfma_f32_16x16x32_bf16(A0, B0, acc[T], 0, 0, 0); \
            short8v B1 = *reinterpret_cast<const short8v*>(&xv_[bb_ - 16 * (2 + hhi)]); \
            acc[T] = __builtin_amdgcn_mfma_f32_16x16x32_bf16(A1, B1, acc[T], 0, 0, 0); \
            short8v B2 = *reinterpret_cast<const short8v*>(&xv_[bb_ - 16 * (4 + hhi)]); \
            acc[T] = __builtin_amdgcn_mfma_f32_16x16x32_bf16(A2, B2, acc[T], 0, 0, 0); \
        }                                                             \
    }

// ---------------------------------------------------------------------------
// KA: pass A + edge scatter fused in one grid.
//   blocks [0, 8192):    z[n] = h_n (*) x_n  per (node, batch); h_n inline.
//   blocks [8192, 8256): edge scatter (128 edges/block) into slist/cnt.
// The two block families touch disjoint buffers; KB launches after KA.
// cnt zeroed by hipMemsetAsync before this launch.
// ---------------------------------------------------------------------------
__global__ __launch_bounds__(128)
void passA_kernel(const float* __restrict__ x,
                  const float* __restrict__ params,
                  const int* __restrict__ esrc, const int* __restrict__ etgt,
                  unsigned short* __restrict__ z,
                  int* __restrict__ cnt, int* __restrict__ slist) {
    const int tid = threadIdx.x;
    const int bid = blockIdx.x;

    if (bid >= NN * 2) {                        // ---- edge scatter ----
        int e = (bid - NN * 2) * 128 + tid;
        int t = etgt[e], s = esrc[e];
        int pos = atomicAdd(&cnt[t], 1);
        if (pos < CAP) slist[t * CAP + pos] = s;
        return;
    }

    __shared__ ConvLds lds;
    const int b      = bid & 1;
    const int node   = bid >> 1;
    const int l      = tid & 63;
    const int lane16 = l & 15;
    const int h      = l >> 4;
    const int hlo    = h & 1, hhi = h >> 1;
    const int half   = tid >> 6;

    // issue x loads first; IRF + LDS init run under their latency
    const float4* xr = reinterpret_cast<const float4*>(x + ((size_t)b * NN + node) * TT);
    float4 px[4];
    #pragma unroll
    for (int c = 0; c < 4; ++c) px[c] = xr[tid + 128 * c];
    unsigned short kb = irf_lane(params, node, l);

    for (int idx = tid; idx < HALO; idx += 128) lds.xrow[idx] = 0;
    TAB_ZERO_INIT(lds);

    #pragma unroll
    for (int c = 0; c < 4; ++c) {
        int u = tid + 128 * c;
        unsigned lo = cvtpk_bf16(px[c].x, px[c].y);
        unsigned hi = cvtpk_bf16(px[c].z, px[c].w);
        *reinterpret_cast<uint2*>(&lds.xrow[HALO + 4 * u]) = make_uint2(lo, hi);
    }
    TAB_VALUE(lds, kb);
    __syncthreads();

    float4v acc[4];
    #pragma unroll
    for (int T = 0; T < 4; ++T) acc[T] = (float4v){0.f, 0.f, 0.f, 0.f};
    CONV_COMPUTE(lds, acc);

    unsigned short* zr = z + ((size_t)b * NN + node) * TT;
    #pragma unroll
    for (int T = 0; T < 4; ++T) {
        int tb = 16 * (64 * half + 16 * T + lane16) + 4 * h;
        uint2 o = make_uint2(cvtpk_bf16(acc[T][0], acc[T][1]),
                             cvtpk_bf16(acc[T][2], acc[T][3]));
        *reinterpret_cast<uint2*>(&zr[tb]) = o;     // cacheable: re-read by KB
    }
}

// ---------------------------------------------------------------------------
// KB: y[tgt] = z_tgt + h_tgt (*) (sum_e z[src_e]).   NO x read; h_tgt inline.
// One block per (tgt, batch), 128 thr = 2 waves.  Gathered sum in fp32 regs,
// staged bf16; z_tgt loaded in the ACC OUTPUT layout and added post-conv.
// ---------------------------------------------------------------------------
__global__ __launch_bounds__(128)
void passB_kernel(const unsigned short* __restrict__ z,
                  const float* __restrict__ params,
                  const int* __restrict__ slist,
                  const int* __restrict__ cnt,
                  float* __restrict__ y) {
    __shared__ ConvLds lds;
    const int tid    = threadIdx.x;
    const int bid    = blockIdx.x;
    const int b      = bid & 1;
    const int tgt    = bid >> 1;
    const int l      = tid & 63;
    const int lane16 = l & 15;
    const int h      = l >> 4;
    const int hlo    = h & 1, hhi = h >> 1;
    const int half   = tid >> 6;

    // issue z_tgt (output-layout) + metadata loads first
    const unsigned short* ztr = z + ((size_t)b * NN + tgt) * TT;
    uint2 zt[4];
    #pragma unroll
    for (int T = 0; T < 4; ++T) {
        int tb = 16 * (64 * half + 16 * T + lane16) + 4 * h;
        zt[T] = *reinterpret_cast<const uint2*>(&ztr[tb]);
    }
    int deg = __builtin_amdgcn_readfirstlane(cnt[tgt]);
    if (deg > CAP) deg = CAP;
    int sCur = 0;
    if (deg > 0) sCur = __builtin_amdgcn_readfirstlane(slist[tgt * CAP]);
    unsigned short kb = irf_lane(params, tgt, l);

    // LDS init under load latency
    for (int idx = tid; idx < HALO; idx += 128) lds.xrow[idx] = 0;
    TAB_ZERO_INIT(lds);

    // gather sum_e z_src in fp32 (thread owns elems 8*tid.. and 1024+8*tid..)
    float w[16];
    #pragma unroll
    for (int k = 0; k < 16; ++k) w[k] = 0.f;
    for (int j = 0; j < deg; ++j) {
        const short8v* zr = reinterpret_cast<const short8v*>(z + ((size_t)b * NN + sCur) * TT);
        short8v z0 = zr[tid];
        short8v z1 = zr[tid + 128];
        if (j + 1 < deg) sCur = __builtin_amdgcn_readfirstlane(slist[tgt * CAP + j + 1]);
        #pragma unroll
        for (int k = 0; k < 8; ++k) {
            w[k]     += bf2f((unsigned short)z0[k]);
            w[8 + k] += bf2f((unsigned short)z1[k]);
        }
    }

    // stage w (bf16) + tab value band
    {
        uint4 o;
        o.x = cvtpk_bf16(w[0], w[1]); o.y = cvtpk_bf16(w[2], w[3]);
        o.z = cvtpk_bf16(w[4], w[5]); o.w = cvtpk_bf16(w[6], w[7]);
        *reinterpret_cast<uint4*>(&lds.xrow[HALO + 8 * tid]) = o;
        o.x = cvtpk_bf16(w[8], w[9]);   o.y = cvtpk_bf16(w[10], w[11]);
        o.z = cvtpk_bf16(w[12], w[13]); o.w = cvtpk_bf16(w[14], w[15]);
        *reinterpret_cast<uint4*>(&lds.xrow[HALO + 1024 + 8 * tid]) = o;
    }
    TAB_VALUE(lds, kb);
    __syncthreads();

    float4v acc[4];
    #pragma unroll
    for (int T = 0; T < 4; ++T) acc[T] = (float4v){0.f, 0.f, 0.f, 0.f};
    CONV_COMPUTE(lds, acc);

    float* yrow = y + ((size_t)b * NN + tgt) * TT;
    #pragma unroll
    for (int T = 0; T < 4; ++T) {
        int tb = 16 * (64 * half + 16 * T + lane16) + 4 * h;
        float4v v = acc[T];
        v[0] += bf2f((unsigned short)(zt[T].x & 0xffffu));
        v[1] += bf2f((unsigned short)(zt[T].x >> 16));
        v[2] += bf2f((unsigned short)(zt[T].y & 0xffffu));
        v[3] += bf2f((unsigned short)(zt[T].y >> 16));
        __builtin_nontemporal_store(v, reinterpret_cast<float4v*>(yrow + tb));
    }
}

// ---------------------------------------------------------------------------
extern "C" void kernel_launch(void* const* d_in, const int* in_sizes, int n_in,
                              void* d_out, int out_size, void* d_ws, size_t ws_size,
                              hipStream_t stream) {
    const float* x      = (const float*)d_in[0];
    const float* params = (const float*)d_in[1];
    const int*   esrc   = (const int*)d_in[2];
    const int*   etgt   = (const int*)d_in[3];
    float* y = (float*)d_out;

    char* w = (char*)d_ws;
    int*            cnt   = (int*)w;            w += (size_t)NN * 4;            // 16 KB
    int*            slist = (int*)w;            w += (size_t)NN * CAP * 4;      // 0.5 MB
    unsigned short* z     = (unsigned short*)w; w += (size_t)2 * NN * TT * 2;   // 32 MB
    (void)ws_size;

    hipMemsetAsync(cnt, 0, (size_t)NN * 4, stream);
    hipLaunchKernelGGL(passA_kernel, dim3(NN * 2 + EE / 128), dim3(128), 0, stream,
                       x, params, esrc, etgt, z, cnt, slist);
    hipLaunchKernelGGL(passB_kernel, dim3(NN * 2), dim3(128), 0, stream,
                       z, params, slist, cnt, y);
}